// Round 2
// baseline (2300.478 us; speedup 1.0000x reference)
//
#include <hip/hip_runtime.h>
#include <cstdio>
#include <cstdint>

// HeteroGraph 3-layer SAGE on MI355X.
// Key structure: agr/urb aggregations computed ONCE (features constant across
// layers); per-layer fused 4-term GEMM with mean-scale folded into epilogue;
// CSR (hist->scan->fill) + wave-per-dst aggregation => no per-feature atomics.
// OUTPUT IS FLOAT32 (reference returns f32 softmax) — round-1 bug was bf16 out.

#define NSUB 200000
#define HDIM 64
#define ESS 2000000
#define EAS 4000000
#define EUS 2000000
#define CDIV(a,b) (((a)+(b)-1)/(b))

using u16 = unsigned short;

__device__ __forceinline__ float bu2f(u16 u){
  union { unsigned int i; float f; } c; c.i = ((unsigned int)u) << 16; return c.f;
}
__device__ __forceinline__ u16 f2bu(float x){
  union { float f; unsigned int i; } c; c.f = x;
  unsigned int r = c.i + 0x7fffu + ((c.i >> 16) & 1u);
  return (u16)(r >> 16);
}

__global__ void kzero(int* __restrict__ p, int n){
  int i = blockIdx.x*256 + threadIdx.x; if(i<n) p[i]=0;
}

__global__ void khist(const int* __restrict__ dst, int E, int* __restrict__ deg){
  int i = blockIdx.x*256 + threadIdx.x; if(i<E) atomicAdd(&deg[dst[i]],1);
}

// block-local exclusive scan over 1024 elems (256 thr x 4)
__global__ void kscan1(const int* __restrict__ deg, int* __restrict__ rp,
                       int* __restrict__ bsum, int n){
  __shared__ int lds[256];
  int t = threadIdx.x;
  int base = blockIdx.x*1024 + t*4;
  int v0 = (base+0<n)?deg[base+0]:0;
  int v1 = (base+1<n)?deg[base+1]:0;
  int v2 = (base+2<n)?deg[base+2]:0;
  int v3 = (base+3<n)?deg[base+3]:0;
  int tot = v0+v1+v2+v3;
  lds[t]=tot; __syncthreads();
  for(int off=1; off<256; off<<=1){
    int x = lds[t];
    int y = (t>=off)?lds[t-off]:0;
    __syncthreads();
    lds[t] = x+y;
    __syncthreads();
  }
  int run = lds[t]-tot;
  if(base+0<n) rp[base+0]=run; run+=v0;
  if(base+1<n) rp[base+1]=run; run+=v1;
  if(base+2<n) rp[base+2]=run; run+=v2;
  if(base+3<n) rp[base+3]=run;
  if(t==255) bsum[blockIdx.x]=lds[255];
}

__global__ void kscan2(int* __restrict__ bsum, int nb){
  __shared__ int lds[256];
  int t = threadIdx.x;
  int v = (t<nb)?bsum[t]:0;
  lds[t]=v; __syncthreads();
  for(int off=1; off<256; off<<=1){
    int x = lds[t];
    int y = (t>=off)?lds[t-off]:0;
    __syncthreads();
    lds[t] = x+y;
    __syncthreads();
  }
  int excl = lds[t]-v;
  if(t<nb) bsum[t]=excl;
}

__global__ void kscan3(int* __restrict__ rp, const int* __restrict__ bsum, int n){
  int i = blockIdx.x*256 + threadIdx.x; if(i<n) rp[i]+=bsum[i>>10];
}

__global__ void kcopy(int* __restrict__ d, const int* __restrict__ s, int n){
  int i = blockIdx.x*256 + threadIdx.x; if(i<n) d[i]=s[i];
}

__global__ void kfill(const int* __restrict__ src, const int* __restrict__ dst,
                      int E, int* __restrict__ cursor, int* __restrict__ col){
  int i = blockIdx.x*256 + threadIdx.x;
  if(i<E){ int pos = atomicAdd(&cursor[dst[i]],1); col[pos]=src[i]; }
}

__global__ void kcast(const float4* __restrict__ in, uint2* __restrict__ outp, int n4){
  int i = blockIdx.x*256 + threadIdx.x;
  if(i<n4){
    float4 v = in[i];
    uint2 o;
    o.x = (unsigned int)f2bu(v.x) | ((unsigned int)f2bu(v.y)<<16);
    o.y = (unsigned int)f2bu(v.z) | ((unsigned int)f2bu(v.w)<<16);
    outp[i]=o;
  }
}

__global__ void kinvdeg(const int* __restrict__ deg, float* __restrict__ inv, int n){
  int i = blockIdx.x*256 + threadIdx.x;
  if(i<n){ int d = deg[i]; inv[i] = 1.0f / (float)(d>1?d:1); }
}

__device__ __forceinline__ float gather1(const float* x, size_t idx){ return x[idx]; }
__device__ __forceinline__ float gather1(const u16* x, size_t idx){ return bu2f(x[idx]); }

// one wave per dst node; lane = feature. No atomics; coalesced row reads.
template<typename T>
__global__ void kaggregate(const T* __restrict__ x, const int* __restrict__ rowptr,
                           const int* __restrict__ deg, const int* __restrict__ col,
                           u16* __restrict__ out, int ndst){
  int gid = blockIdx.x*256 + threadIdx.x;
  int w = gid>>6, lane = gid&63;
  if(w>=ndst) return;
  int s = rowptr[w], d = deg[w];
  float acc = 0.f;
  int i=0;
  for(; i+4<=d; i+=4){
    int s0=col[s+i], s1=col[s+i+1], s2=col[s+i+2], s3=col[s+i+3];
    float a0 = gather1(x, (size_t)s0*HDIM + lane);
    float a1 = gather1(x, (size_t)s1*HDIM + lane);
    float a2 = gather1(x, (size_t)s2*HDIM + lane);
    float a3 = gather1(x, (size_t)s3*HDIM + lane);
    acc += (a0+a1)+(a2+a3);
  }
  for(; i<d; i++){
    int s0=col[s+i];
    acc += gather1(x, (size_t)s0*HDIM + lane);
  }
  out[(size_t)w*HDIM + lane] = f2bu(acc);
}

__device__ __forceinline__ void stage_in(float* ldsIn, const u16* a, int base, int koff, int tid){
  const unsigned int* a32 = (const unsigned int*)(a + (size_t)base*HDIM);
  #pragma unroll
  for(int j=0;j<8;j++){
    int idx = j*256+tid;
    unsigned int v = a32[idx];
    int r = idx>>5, k2 = idx&31;
    ldsIn[r*257 + koff + 2*k2]   = bu2f((u16)(v & 0xffffu));
    ldsIn[r*257 + koff + 2*k2+1] = bu2f((u16)(v >> 16));
  }
}

#define FMA16(ACC) \
  ACC[0]+=a*w0.x; ACC[1]+=a*w0.y; ACC[2]+=a*w0.z; ACC[3]+=a*w0.w; \
  ACC[4]+=a*w1.x; ACC[5]+=a*w1.y; ACC[6]+=a*w1.z; ACC[7]+=a*w1.w; \
  ACC[8]+=a*w2.x; ACC[9]+=a*w2.y; ACC[10]+=a*w2.z; ACC[11]+=a*w2.w; \
  ACC[12]+=a*w3.x; ACC[13]+=a*w3.y; ACC[14]+=a*w3.z; ACC[15]+=a*w3.w;

// fused: h = relu(scale*(aggSS@Wl0^T) + aggAS@Wl1^T + aggUS@Wl2^T
//                 + sub@(Wr0+Wr1+Wr2)^T + (bl0+bl1+bl2))
// 64 rows/block, 256 threads: wave g handles outputs [g*16, g*16+16), lane = row.
__global__ __launch_bounds__(256,1) void kgemm(
    const u16* __restrict__ aggSS, const u16* __restrict__ aggAS,
    const u16* __restrict__ aggUS, const u16* __restrict__ subIn,
    const float* __restrict__ Wl3, const float* __restrict__ Wr3,
    const float* __restrict__ bl3, const float* __restrict__ invdeg,
    u16* __restrict__ subOut)
{
  __shared__ float ldsW[256*68];   // [k'][o] pad 68 -> 16B-aligned float4 rows
  __shared__ float ldsIn[64*257];  // [row][k'] pad 257
  __shared__ float ldsB[64];
  __shared__ float ldsS[64];
  const int tid = threadIdx.x;
  const int base = blockIdx.x*64;

  #pragma unroll
  for(int j=0;j<48;j++){                 // Wl: 3 relations x 64x64, coalesced in k
    int idx = j*256+tid;
    int rel = idx>>12, rem = idx&4095;
    int o = rem>>6, k = rem&63;
    ldsW[(rel*64+k)*68 + o] = Wl3[idx];
  }
  #pragma unroll
  for(int j=0;j<16;j++){                 // WrSum
    int idx = j*256+tid;
    int o = idx>>6, k = idx&63;
    ldsW[(192+k)*68 + o] = Wr3[idx] + Wr3[4096+idx] + Wr3[8192+idx];
  }
  if(tid<64){
    ldsB[tid] = bl3[tid] + bl3[64+tid] + bl3[128+tid];
    ldsS[tid] = invdeg ? invdeg[base+tid] : 1.0f;
  }
  stage_in(ldsIn, aggSS, base, 0,   tid);
  stage_in(ldsIn, aggAS, base, 64,  tid);
  stage_in(ldsIn, aggUS, base, 128, tid);
  stage_in(ldsIn, subIn, base, 192, tid);
  __syncthreads();

  const int lane = tid&63, g = tid>>6;
  const float* inRow = &ldsIn[lane*257];
  float accS[16], accR[16];
  #pragma unroll
  for(int j=0;j<16;j++){ accS[j]=0.f; accR[j]=0.f; }

  #pragma unroll 8
  for(int k=0;k<64;k++){
    float a = inRow[k];
    const float* wr = &ldsW[k*68 + g*16];
    float4 w0 = *(const float4*)(wr+0);
    float4 w1 = *(const float4*)(wr+4);
    float4 w2 = *(const float4*)(wr+8);
    float4 w3 = *(const float4*)(wr+12);
    FMA16(accS)
  }
  #pragma unroll 8
  for(int k=64;k<256;k++){
    float a = inRow[k];
    const float* wr = &ldsW[k*68 + g*16];
    float4 w0 = *(const float4*)(wr+0);
    float4 w1 = *(const float4*)(wr+4);
    float4 w2 = *(const float4*)(wr+8);
    float4 w3 = *(const float4*)(wr+12);
    FMA16(accR)
  }

  float scale = ldsS[lane];
  float h[16];
  #pragma unroll
  for(int j=0;j<16;j++){
    float v = accS[j]*scale + accR[j] + ldsB[g*16+j];
    h[j] = fmaxf(v, 0.f);
  }
  unsigned int p[8];
  #pragma unroll
  for(int j=0;j<8;j++)
    p[j] = (unsigned int)f2bu(h[2*j]) | ((unsigned int)f2bu(h[2*j+1])<<16);
  unsigned int* op = (unsigned int*)(subOut + (size_t)(base+lane)*HDIM + g*16);
  uint4 pa; pa.x=p[0]; pa.y=p[1]; pa.z=p[2]; pa.w=p[3];
  uint4 pb; pb.x=p[4]; pb.y=p[5]; pb.z=p[6]; pb.w=p[7];
  *(uint4*)op = pa;
  *(uint4*)(op+4) = pb;
}

// head: softmax(sub @ Wf^T + bf) -> FLOAT32 out (reference output dtype)
__global__ void khead(const u16* __restrict__ sub, const float* __restrict__ Wf,
                      const float* __restrict__ bfv, float* __restrict__ out, int n){
  __shared__ float w[6*64];
  __shared__ float b[6];
  for(int j=threadIdx.x; j<384; j+=256) w[j]=Wf[j];
  if(threadIdx.x<6) b[threadIdx.x]=bfv[threadIdx.x];
  __syncthreads();
  int i = blockIdx.x*256 + threadIdx.x;
  if(i>=n) return;
  const unsigned int* row = (const unsigned int*)(sub + (size_t)i*HDIM);
  float d0=b[0],d1=b[1],d2=b[2],d3=b[3],d4=b[4],d5=b[5];
  #pragma unroll 8
  for(int k2=0;k2<32;k2++){
    unsigned int v = row[k2];
    float lo = bu2f((u16)(v&0xffffu));
    float hi = bu2f((u16)(v>>16));
    int k = 2*k2;
    d0 += lo*w[0*64+k] + hi*w[0*64+k+1];
    d1 += lo*w[1*64+k] + hi*w[1*64+k+1];
    d2 += lo*w[2*64+k] + hi*w[2*64+k+1];
    d3 += lo*w[3*64+k] + hi*w[3*64+k+1];
    d4 += lo*w[4*64+k] + hi*w[4*64+k+1];
    d5 += lo*w[5*64+k] + hi*w[5*64+k+1];
  }
  float m = fmaxf(fmaxf(fmaxf(d0,d1),fmaxf(d2,d3)),fmaxf(d4,d5));
  float e0=expf(d0-m), e1=expf(d1-m), e2=expf(d2-m);
  float e3=expf(d3-m), e4=expf(d4-m), e5=expf(d5-m);
  float inv = 1.0f/(e0+e1+e2+e3+e4+e5);
  float2* op = (float2*)(out + (size_t)i*6);
  float2 r0; r0.x=e0*inv; r0.y=e1*inv;
  float2 r1; r1.x=e2*inv; r1.y=e3*inv;
  float2 r2; r2.x=e4*inv; r2.y=e5*inv;
  op[0]=r0; op[1]=r1; op[2]=r2;
}

extern "C" void kernel_launch(void* const* d_in, const int* in_sizes, int n_in,
                              void* d_out, int out_size, void* d_ws, size_t ws_size,
                              hipStream_t stream) {
  const float* x_sub = (const float*)d_in[0];
  const float* x_agr = (const float*)d_in[1];
  const float* x_urb = (const float*)d_in[2];
  const float* Wl    = (const float*)d_in[3];  // [3][3][64][64]
  const float* bl    = (const float*)d_in[4];  // [3][3][64]
  const float* Wr    = (const float*)d_in[5];  // [3][3][64][64]
  const float* Wf    = (const float*)d_in[6];  // [6][64]
  const float* bfv   = (const float*)d_in[7];  // [6]
  const int* e_ss    = (const int*)d_in[8];    // [2][ESS]
  const int* e_as_s  = (const int*)d_in[9];
  const int* e_as_d  = (const int*)d_in[10];
  const int* e_us    = (const int*)d_in[11];   // [2][EUS]
  float* out = (float*)d_out;

  char* ws = (char*)d_ws;
  size_t off = 0;
  auto alloc = [&](size_t bytes)->void*{
    void* p = ws + off; off += (bytes + 255) & ~(size_t)255; return p;
  };
  u16*  subA   = (u16*) alloc((size_t)NSUB*HDIM*2);
  u16*  subB   = (u16*) alloc((size_t)NSUB*HDIM*2);
  u16*  aggSS  = (u16*) alloc((size_t)NSUB*HDIM*2);
  u16*  aggAS  = (u16*) alloc((size_t)NSUB*HDIM*2);
  u16*  aggUS  = (u16*) alloc((size_t)NSUB*HDIM*2);
  float* invdeg= (float*)alloc((size_t)NSUB*4);
  int*  deg_ss = (int*)  alloc((size_t)NSUB*4);
  int*  deg_as = (int*)  alloc((size_t)NSUB*4);
  int*  deg_us = (int*)  alloc((size_t)NSUB*4);
  int*  rp_ss  = (int*)  alloc((size_t)NSUB*4);
  int*  rp_as  = (int*)  alloc((size_t)NSUB*4);
  int*  rp_us  = (int*)  alloc((size_t)NSUB*4);
  int*  cursor = (int*)  alloc((size_t)NSUB*4);
  int*  bsum   = (int*)  alloc(1024);
  int*  col_ss = (int*)  alloc((size_t)ESS*4);
  int*  col_as = (int*)  alloc((size_t)EAS*4);
  int*  col_us = (int*)  alloc((size_t)EUS*4);
  if(off > ws_size){
    fprintf(stderr, "kernel_launch: ws too small: need %zu have %zu\n", off, ws_size);
    return;
  }

  const int nsb = CDIV(NSUB,256);
  const int nscan = CDIV(NSUB,1024);   // 196

  // zero the 3 degree arrays (contiguous)
  kzero<<<CDIV(3*NSUB,256),256,0,stream>>>(deg_ss, 3*NSUB);

  // histograms
  khist<<<CDIV(ESS,256),256,0,stream>>>(e_ss + ESS, ESS, deg_ss);
  khist<<<CDIV(EAS,256),256,0,stream>>>(e_as_d,     EAS, deg_as);
  khist<<<CDIV(EUS,256),256,0,stream>>>(e_us + EUS, EUS, deg_us);

  // exclusive scans -> rowptrs
  kscan1<<<nscan,256,0,stream>>>(deg_ss, rp_ss, bsum, NSUB);
  kscan2<<<1,256,0,stream>>>(bsum, nscan);
  kscan3<<<nsb,256,0,stream>>>(rp_ss, bsum, NSUB);
  kscan1<<<nscan,256,0,stream>>>(deg_as, rp_as, bsum, NSUB);
  kscan2<<<1,256,0,stream>>>(bsum, nscan);
  kscan3<<<nsb,256,0,stream>>>(rp_as, bsum, NSUB);
  kscan1<<<nscan,256,0,stream>>>(deg_us, rp_us, bsum, NSUB);
  kscan2<<<1,256,0,stream>>>(bsum, nscan);
  kscan3<<<nsb,256,0,stream>>>(rp_us, bsum, NSUB);

  // fill CSR cols
  kcopy<<<nsb,256,0,stream>>>(cursor, rp_ss, NSUB);
  kfill<<<CDIV(ESS,256),256,0,stream>>>(e_ss, e_ss + ESS, ESS, cursor, col_ss);
  kcopy<<<nsb,256,0,stream>>>(cursor, rp_as, NSUB);
  kfill<<<CDIV(EAS,256),256,0,stream>>>(e_as_s, e_as_d, EAS, cursor, col_as);
  kcopy<<<nsb,256,0,stream>>>(cursor, rp_us, NSUB);
  kfill<<<CDIV(EUS,256),256,0,stream>>>(e_us, e_us + EUS, EUS, cursor, col_us);

  // x_sub -> bf16, invdeg
  kcast<<<CDIV(NSUB*HDIM/4,256),256,0,stream>>>((const float4*)x_sub, (uint2*)subA, NSUB*HDIM/4);
  kinvdeg<<<nsb,256,0,stream>>>(deg_ss, invdeg, NSUB);

  // one-time agr/urb aggregations (features constant across layers)
  const int aggBlocks = CDIV(NSUB*64,256);
  kaggregate<float><<<aggBlocks,256,0,stream>>>(x_agr, rp_as, deg_as, col_as, aggAS, NSUB);
  kaggregate<float><<<aggBlocks,256,0,stream>>>(x_urb, rp_us, deg_us, col_us, aggUS, NSUB);

  const int gemmBlocks = NSUB/64;  // 3125, exact
  // layer 0 (ss aggr = sum)
  kaggregate<u16><<<aggBlocks,256,0,stream>>>(subA, rp_ss, deg_ss, col_ss, aggSS, NSUB);
  kgemm<<<gemmBlocks,256,0,stream>>>(aggSS, aggAS, aggUS, subA,
      Wl + 0*3*4096, Wr + 0*3*4096, bl + 0*3*64, nullptr, subB);
  // layer 1 (ss aggr = mean)
  kaggregate<u16><<<aggBlocks,256,0,stream>>>(subB, rp_ss, deg_ss, col_ss, aggSS, NSUB);
  kgemm<<<gemmBlocks,256,0,stream>>>(aggSS, aggAS, aggUS, subB,
      Wl + 1*3*4096, Wr + 1*3*4096, bl + 1*3*64, invdeg, subA);
  // layer 2 (ss aggr = mean)
  kaggregate<u16><<<aggBlocks,256,0,stream>>>(subA, rp_ss, deg_ss, col_ss, aggSS, NSUB);
  kgemm<<<gemmBlocks,256,0,stream>>>(aggSS, aggAS, aggUS, subA,
      Wl + 2*3*4096, Wr + 2*3*4096, bl + 2*3*64, invdeg, subB);

  // head: softmax(sub @ Wf^T + bf) -> f32 out
  khead<<<nsb,256,0,stream>>>(subB, Wf, bfv, out, NSUB);
}